// Round 7
// baseline (212.598 us; speedup 1.0000x reference)
//
#include <hip/hip_runtime.h>
#include <hip/hip_bf16.h>

#define BATCH 4096
#define NTHR 512

typedef __attribute__((ext_vector_type(8))) short bf16x8;
typedef __attribute__((ext_vector_type(4))) float f32x4;
typedef __attribute__((ext_vector_type(4))) short short4v;

// CK-style barrier: drain LDS only, leave global prefetches in flight
#define BAR() asm volatile("s_waitcnt lgkmcnt(0)\n\ts_barrier" ::: "memory")

// dh-sorted packing: group g (= degree) has cnt(g) units, prefix off1(g)
__host__ __device__ __forceinline__ int off1(int g) { return (g <= 16) ? 17 * g : 16 * g + 16; }
__host__ __device__ __forceinline__ int cntg(int g) { return (g < 16) ? 17 : 16; }
__host__ __device__ __forceinline__ int unitOf(int p) {
    int gp, jp;
    if (p < 272) { gp = p / 17; jp = p - gp * 17; }
    else         { gp = (p >> 4) - 1; jp = p & 15; }
    return gp + 63 * jp;
}
__device__ __forceinline__ short f2bf(float f) {
    __hip_bfloat16 h = __float2bfloat16(f);
    return *reinterpret_cast<short*>(&h);
}

// ---------------- prep7: LDS-staged coalesced packing (padded stage: no 16-way conflicts) ----
// W1f [g][tile(64)][lane][8] : B[k][n] = W1[unit(tile*16+n)][g+63k], k<cnt(g)
// W2f [g][c(8)][lane][8]     : packed z col pc=c*16+n -> orig r=(pc>>1)+64*(pc&1)
// W0f [g][f(4)][lane][8]     : f=n2*2+kt; slot p=off1(g)+n2*16+(lane&15);
//     kp=kt*32+(lane>>4)*8+e; kp==0 -> b0[unit(p)]; kp-1<=g -> W0[unit(p)][kp-1]; else 0
// b1p [1024] f32 packed b1
__global__ void prep7(const float* __restrict__ W0, const float* __restrict__ b0,
                      const float* __restrict__ W1, const float* __restrict__ b1,
                      const float* __restrict__ W2,
                      short* __restrict__ W1f, short* __restrict__ W2f,
                      short* __restrict__ W0f, float* __restrict__ b1p) {
    __shared__ short ws[16][1032];   // +8 pad: row offset 516 dwords -> 4-bank skew, 2-way max
    const int b = blockIdx.x, t = threadIdx.x;
    if (b < 72) {
        const bool isW1 = (b < 64);
        const int n = t >> 5;                 // staged slot 0..15
        int u;
        if (isW1) u = unitOf(b * 16 + n);
        else { const int c = b - 64; u = (n & 1) ? (64 + c * 8 + (n >> 1)) : (c * 8 + (n >> 1)); }
        const float* src = isW1 ? (W1 + (long)u * 1024) : (W2 + (long)u * 1024);
        const int c0 = (t & 31) * 4;
#pragma unroll
        for (int j = 0; j < 8; ++j) {
            int c = c0 + j * 128;
            float4 v = *(const float4*)&src[c];
            short4v sv;
            sv[0] = f2bf(v.x); sv[1] = f2bf(v.y); sv[2] = f2bf(v.z); sv[3] = f2bf(v.w);
            *(short4v*)&ws[n][c] = sv;
        }
        __syncthreads();
#pragma unroll 1
        for (int it = 0; it < 8; ++it) {
            int v = t + it * 512;
            if (v < 4032) {
                int g = v >> 6, lane2 = v & 63;
                int nn = lane2 & 15, aq2 = lane2 >> 4;
                bf16x8 pk;
#pragma unroll
                for (int e = 0; e < 8; ++e) {
                    int k = aq2 * 8 + e;
                    pk[e] = (k < cntg(g)) ? ws[nn][g + 63 * k] : (short)0;
                }
                if (isW1) *(bf16x8*)&W1f[(((long)g * 64 + b) * 64 + lane2) * 8] = pk;
                else      *(bf16x8*)&W2f[(((long)g * 8 + (b - 64)) * 64 + lane2) * 8] = pk;
            }
        }
    } else if (b < 88) {
        const int bb = b - 72;
#pragma unroll 1
        for (int j = 0; j < 16; ++j) {
            int q = t + j * 512;
            if (q < 8064) {
                int idx = bb * 8064 + q;
                int g = idx >> 11, rem = idx & 2047;
                int n2 = rem >> 10, kt = (rem >> 9) & 1, lane2 = (rem >> 3) & 63, e = rem & 7;
                int sl = n2 * 16 + (lane2 & 15);
                int kp = kt * 32 + ((lane2 >> 4) << 3) + e;
                float val = 0.f;
                if (sl < cntg(g)) {
                    int u = unitOf(off1(g) + sl);
                    if (kp == 0) val = b0[u];
                    else if (kp - 1 <= g) val = W0[u * 64 + kp - 1];
                }
                W0f[idx] = f2bf(val);
            }
        }
    } else {
        for (int p = t; p < 1024; p += 512) b1p[p] = b1[unitOf(p)];
    }
}

// ---------------- made7: SINGLE window per step ----------------
// Ownership: wave w finalizes h2[g] for g in [8w-1, 8w+6]  ==> owns tiles:
//   w=0: 0..7 (8) | w=1: 7..15 (9) | w=2: 15..23 (9) | w>=3: 8w..8w+7 (8)
// (tiles 7 and 15 duplicated in two waves; each keeps a full independent accumulator)
// Publisher of step i = wave i>>3 = finalizer of h2[i-1]: the whole chain
// h2-finalize -> z -> x -> h1[i] is same-wave (lgkmcnt round-trips, no barrier).
// Non-publishers update their z columns with LAG-1 (group g-1 from parity buffer).
__global__ __launch_bounds__(NTHR, 2) void made7(
    const float* __restrict__ uin, const float* __restrict__ b2,
    const short* __restrict__ W1f, const short* __restrict__ W2f,
    const short* __restrict__ W0f, const float* __restrict__ b1p,
    float* __restrict__ out) {

    __shared__ __align__(16) short h1b[2][16][40];   // parity buffers, [m][j], K-pad zeroed
    __shared__ __align__(16) short h2b[2][16][40];
    __shared__ __align__(16) short xhist[16][80];    // [m][k']: k'=0 -> 1.0, k'=i+1 -> x_i
    __shared__ __align__(16) float uT[64][16];
    __shared__ __align__(16) float xLs[16][68];
    __shared__ float ldjpart[8][16];

    const int t = threadIdx.x, lane = t & 63, wv = t >> 6;
    const int n = lane & 15, aq = lane >> 4;
    const int rowbase = blockIdx.x * 16;

    {   // zero all parity buffers + xhist (K pads must stay 0)
        int* z1 = (int*)&h1b[0][0][0];
        for (int idx = t; idx < 2 * 16 * 40 / 2; idx += NTHR) z1[idx] = 0;
        int* z2 = (int*)&h2b[0][0][0];
        for (int idx = t; idx < 2 * 16 * 40 / 2; idx += NTHR) z2[idx] = 0;
        int* z3 = (int*)&xhist[0][0];
        for (int idx = t; idx < 16 * 80 / 2; idx += NTHR) z3[idx] = 0;
    }
    if (t < 256) {
        int r = t >> 4, c0 = (t & 15) * 4;
        float4 v = *(const float4*)&uin[(long)(rowbase + r) * 64 + c0];
        uT[c0 + 0][r] = v.x; uT[c0 + 1][r] = v.y; uT[c0 + 2][r] = v.z; uT[c0 + 3][r] = v.w;
    }

    const int B = (wv == 0) ? 0 : (wv == 1) ? 7 : (wv == 2) ? 15 : 8 * wv;
    const int C = (wv == 1 || wv == 2) ? 9 : 8;

    f32x4 acc2[9];
#pragma unroll
    for (int s = 0; s < 9; ++s) {
        float bb = (s < C) ? b1p[(B + s) * 16 + n] : 0.f;
        acc2[s] = (f32x4){bb, bb, bb, bb};
    }
    f32x4 zacc;
    {
        int pc = wv * 16 + n;
        float bz = b2[(pc >> 1) + 64 * (pc & 1)];
        zacc = (f32x4){bz, bz, bz, bz};
    }

    bf16x8 w1f[9], w2g, w2gm1, w0f0, w0f1, w0f2;
#pragma unroll
    for (int s = 0; s < 9; ++s)
        if (s < C)
            w1f[s] = *(const bf16x8*)&W1f[(((long)0 * 64 + (B + s)) * 64 + lane) * 8]; // g=0
    w2g = *(const bf16x8*)&W2f[(((long)0 * 8 + wv) * 64 + lane) * 8];                  // g=0
    w2gm1 = w2g;
    {
        const long gb = 8 * wv;   // first group this wave computes h1 for
        w0f0 = *(const bf16x8*)&W0f[((gb * 4 + 0) * 64 + lane) * 8];
        w0f1 = *(const bf16x8*)&W0f[((gb * 4 + 1) * 64 + lane) * 8];
        w0f2 = *(const bf16x8*)&W0f[((gb * 4 + 2) * 64 + lane) * 8];
    }

    f32x4 ldjacc = {0.f, 0.f, 0.f, 0.f};
    BAR();
    if (t < 16) xhist[t][0] = (short)0x3F80;   // bias column = 1.0 (wave 0)
    float ureg[4];
#pragma unroll
    for (int r = 0; r < 4; ++r) ureg[r] = uT[8 * wv + (n >> 1)][aq * 4 + r];

#pragma unroll 1
    for (int i = 0; i < 64; ++i) {
        const int g = i - 1;
        const bool isPub = (wv == (i >> 3));

        if (g >= 0) {
            const int og = off1(g);
            const int tf0 = og >> 4;
            // bulk: acc2 += h1[g] * W1 on owned, still-live tiles
            const bf16x8 af1 = *(const bf16x8*)&h1b[(i + 1) & 1][n][aq * 8];
            const int s0 = tf0 - B;
#pragma unroll
            for (int s = 0; s < 9; ++s)
                if (s < C && s >= s0)
                    acc2[s] = __builtin_amdgcn_mfma_f32_16x16x32_bf16(af1, w1f[s], acc2[s], 0, 0, 0);
            {   // prefetch W1f group i (consumed next window)
                const int gp = (i < 63) ? i : 62;
                const int s0p = (off1(gp) >> 4) - B;
#pragma unroll
                for (int s = 0; s < 9; ++s)
                    if (s < C && s >= s0p)
                        w1f[s] = *(const bf16x8*)&W1f[(((long)gp * 64 + (B + s)) * 64 + lane) * 8];
            }
            // z lag-1 update for non-publishers (publisher of i-1 already did g-1 fresh)
            const bool freshedPrev = (wv == ((i - 1) >> 3));
            if (!isPub && !freshedPrev && g >= 1) {
                const bf16x8 af2p = *(const bf16x8*)&h2b[(i - 1) & 1][n][aq * 8];
                zacc = __builtin_amdgcn_mfma_f32_16x16x32_bf16(af2p, w2gm1, zacc, 0, 0, 0);
            }
        }

        if (isPub) {
            if (g >= 0) {
                const int og = off1(g), cg = cntg(g);
                const int tf0 = og >> 4, tfl = (og + cg - 1) >> 4;
                if ((i & 7) == 0 && g >= 1) {   // run-start: catch up group g-1 (lag)
                    const bf16x8 af2p = *(const bf16x8*)&h2b[(i - 1) & 1][n][aq * 8];
                    zacc = __builtin_amdgcn_mfma_f32_16x16x32_bf16(af2p, w2gm1, zacc, 0, 0, 0);
                }
                // finalize h2[g] from own accumulators (this wave owns tf0 and tfl)
                {
                    const int sT = tf0 - B;
                    const int j = tf0 * 16 + n - og;
                    if (j >= 0 && j < cg) {
#pragma unroll
                        for (int r = 0; r < 4; ++r) {
                            float v = acc2[sT][r];
                            h2b[i & 1][aq * 4 + r][j] = f2bf(v > 0.f ? v : 0.f);
                        }
                    }
                }
                if (tfl != tf0) {
                    const int sT = tfl - B;
                    const int j = tfl * 16 + n - og;
                    if (j < cg) {
#pragma unroll
                        for (int r = 0; r < 4; ++r) {
                            float v = acc2[sT][r];
                            h2b[i & 1][aq * 4 + r][j] = f2bf(v > 0.f ? v : 0.f);
                        }
                    }
                }
                if ((g == 16 || g == 17) && n == 0) {   // first 16-wide write per parity: clear col 16
#pragma unroll
                    for (int r = 0; r < 4; ++r) h2b[i & 1][aq * 4 + r][16] = 0;
                }
                // fresh z update with h2[g] (same-wave LDS round trip)
                const bf16x8 af2 = *(const bf16x8*)&h2b[i & 1][n][aq * 8];
                zacc = __builtin_amdgcn_mfma_f32_16x16x32_bf16(af2, w2g, zacc, 0, 0, 0);
            }
            // publish x_i: cols pc=2i (mu), 2i+1 (sigma) live in this wave
            {
                const int n0 = 2 * (i & 7);
                f32x4 sgv;
#pragma unroll
                for (int r = 0; r < 4; ++r) sgv[r] = __shfl_xor(zacc[r], 1);
                if (n == n0) {
#pragma unroll
                    for (int r = 0; r < 4; ++r) {
                        const float sg = sgv[r], mu = zacc[r];
                        const float x = ureg[r] * __expf(sg) + mu;
                        ldjacc[r] += sg;
                        const int m = aq * 4 + r;
                        xLs[m][i] = x;
                        if (i < 63) xhist[m][i + 1] = f2bf(x);
                    }
                }
            }
            if (i < 63) {   // h1[group i] (same-wave xhist round trip)
                const bf16x8 ax0 = *(const bf16x8*)&xhist[n][aq * 8];
                f32x4 d0 = {0.f, 0.f, 0.f, 0.f};
                d0 = __builtin_amdgcn_mfma_f32_16x16x32_bf16(ax0, w0f0, d0, 0, 0, 0);
                if (i >= 31) {
                    const bf16x8 ax1 = *(const bf16x8*)&xhist[n][32 + aq * 8];
                    d0 = __builtin_amdgcn_mfma_f32_16x16x32_bf16(ax1, w0f1, d0, 0, 0, 0);
                }
                f32x4 d1 = {0.f, 0.f, 0.f, 0.f};
                if (i < 16)
                    d1 = __builtin_amdgcn_mfma_f32_16x16x32_bf16(ax0, w0f2, d1, 0, 0, 0);
#pragma unroll
                for (int r = 0; r < 4; ++r) {
                    float v = d0[r];
                    h1b[i & 1][aq * 4 + r][n] = f2bf(v > 0.f ? v : 0.f);
                }
                if (n == 0) {
#pragma unroll
                    for (int r = 0; r < 4; ++r) {
                        float v = (i < 16) ? (d1[r] > 0.f ? d1[r] : 0.f) : 0.f;
                        h1b[i & 1][aq * 4 + r][16] = f2bf(v);
                    }
                }
                if (i + 1 < 63 && ((i + 1) >> 3) == wv) {   // next group still ours
                    const long gb = i + 1;
                    w0f0 = *(const bf16x8*)&W0f[((gb * 4 + 0) * 64 + lane) * 8];
                    w0f1 = *(const bf16x8*)&W0f[((gb * 4 + 1) * 64 + lane) * 8];
                    w0f2 = *(const bf16x8*)&W0f[((gb * 4 + 2) * 64 + lane) * 8];
                }
            }
        }

        // rotate W2 fragments: next window's fresh = group i, lag = group i-1
        w2gm1 = w2g;
        {
            const int gz = (i < 63) ? i : 62;
            w2g = *(const bf16x8*)&W2f[(((long)gz * 8 + wv) * 64 + lane) * 8];
        }
        BAR();
    }

    // ldj: publisher lanes are even n; reduce within wave then across waves
#pragma unroll
    for (int r = 0; r < 4; ++r) {
        float v = ldjacc[r];
        v += __shfl_xor(v, 2);
        v += __shfl_xor(v, 4);
        v += __shfl_xor(v, 8);
        if (n == 0) ldjpart[wv][aq * 4 + r] = v;
    }
    BAR();

    if (t < 256) {
        int r = t >> 4, c = (t & 15) * 4;
        float4 v;
        v.x = xLs[r][c]; v.y = xLs[r][c + 1]; v.z = xLs[r][c + 2]; v.w = xLs[r][c + 3];
        *(float4*)&out[(long)(rowbase + r) * 64 + c] = v;
    }
    if (t < 16) {
        float s = 0.f;
#pragma unroll
        for (int w = 0; w < 8; ++w) s += ldjpart[w][t];
        out[(long)BATCH * 64 + rowbase + t] = s;
    }
}

extern "C" void kernel_launch(void* const* d_in, const int* in_sizes, int n_in,
                              void* d_out, int out_size, void* d_ws, size_t ws_size,
                              hipStream_t stream) {
    (void)in_sizes; (void)n_in; (void)out_size; (void)ws_size;
    const float* u  = (const float*)d_in[0];
    const float* W0 = (const float*)d_in[1];
    const float* b0 = (const float*)d_in[2];
    const float* W1 = (const float*)d_in[3];
    const float* b1 = (const float*)d_in[4];
    const float* W2 = (const float*)d_in[5];
    const float* b2 = (const float*)d_in[6];
    float* out = (float*)d_out;

    // d_ws layout (bytes): W1f 4,128,768 | W2f 516,096 | W0f 258,048 | b1p 4,096
    short* W1f = (short*)d_ws;
    short* W2f = (short*)((char*)d_ws + 4128768);
    short* W0f = (short*)((char*)d_ws + 4128768 + 516096);
    float* b1p = (float*)((char*)d_ws + 4128768 + 516096 + 258048);

    prep7<<<dim3(89), dim3(512), 0, stream>>>(W0, b0, W1, b1, W2, W1f, W2f, W0f, b1p);
    made7<<<dim3(BATCH / 16), dim3(NTHR), 0, stream>>>(u, b2, W1f, W2f, W0f, b1p, out);
}

// Round 8
// 177.530 us; speedup vs baseline: 1.1975x; 1.1975x over previous
//
#include <hip/hip_runtime.h>
#include <hip/hip_bf16.h>

#define BATCH 4096
#define NTHR 512

typedef __attribute__((ext_vector_type(8))) short bf16x8;
typedef __attribute__((ext_vector_type(4))) float f32x4;
typedef __attribute__((ext_vector_type(4))) short short4v;

// CK-style barrier: drain LDS only, leave global prefetches in flight
#define BAR() asm volatile("s_waitcnt lgkmcnt(0)\n\ts_barrier" ::: "memory")

// dh-sorted packing: group g (= degree) has cnt(g) units, prefix off1(g)
__host__ __device__ __forceinline__ int off1(int g) { return (g <= 16) ? 17 * g : 16 * g + 16; }
__host__ __device__ __forceinline__ int cntg(int g) { return (g < 16) ? 17 : 16; }
__host__ __device__ __forceinline__ int unitOf(int p) {
    int gp, jp;
    if (p < 272) { gp = p / 17; jp = p - gp * 17; }
    else         { gp = (p >> 4) - 1; jp = p & 15; }
    return gp + 63 * jp;
}
__device__ __forceinline__ short f2bf(float f) {
    __hip_bfloat16 h = __float2bfloat16(f);
    return *reinterpret_cast<short*>(&h);
}

// ---------------- prep8: LDS-staged coalesced packing ----------------
__global__ void prep8(const float* __restrict__ W0, const float* __restrict__ b0,
                      const float* __restrict__ W1, const float* __restrict__ b1,
                      const float* __restrict__ W2,
                      short* __restrict__ W1f, short* __restrict__ W2f,
                      short* __restrict__ W0f, float* __restrict__ b1p) {
    __shared__ short ws[16][1032];   // +8 pad: 4-bank row skew
    const int b = blockIdx.x, t = threadIdx.x;
    if (b < 72) {
        const bool isW1 = (b < 64);
        const int n = t >> 5;                 // staged slot 0..15
        int u;
        if (isW1) u = unitOf(b * 16 + n);
        else { const int c = b - 64; u = (n & 1) ? (64 + c * 8 + (n >> 1)) : (c * 8 + (n >> 1)); }
        const float* src = isW1 ? (W1 + (long)u * 1024) : (W2 + (long)u * 1024);
        const int c0 = (t & 31) * 4;
#pragma unroll
        for (int j = 0; j < 8; ++j) {
            int c = c0 + j * 128;
            float4 v = *(const float4*)&src[c];
            short4v sv;
            sv[0] = f2bf(v.x); sv[1] = f2bf(v.y); sv[2] = f2bf(v.z); sv[3] = f2bf(v.w);
            *(short4v*)&ws[n][c] = sv;
        }
        __syncthreads();
#pragma unroll 1
        for (int it = 0; it < 8; ++it) {
            int v = t + it * 512;
            if (v < 4032) {
                int g = v >> 6, lane2 = v & 63;
                int nn = lane2 & 15, aq2 = lane2 >> 4;
                bf16x8 pk;
#pragma unroll
                for (int e = 0; e < 8; ++e) {
                    int k = aq2 * 8 + e;
                    pk[e] = (k < cntg(g)) ? ws[nn][g + 63 * k] : (short)0;
                }
                if (isW1) *(bf16x8*)&W1f[(((long)g * 64 + b) * 64 + lane2) * 8] = pk;
                else      *(bf16x8*)&W2f[(((long)g * 8 + (b - 64)) * 64 + lane2) * 8] = pk;
            }
        }
    } else if (b < 88) {
        const int bb = b - 72;
#pragma unroll 1
        for (int j = 0; j < 16; ++j) {
            int q = t + j * 512;
            if (q < 8064) {
                int idx = bb * 8064 + q;
                int g = idx >> 11, rem = idx & 2047;
                int n2 = rem >> 10, kt = (rem >> 9) & 1, lane2 = (rem >> 3) & 63, e = rem & 7;
                int sl = n2 * 16 + (lane2 & 15);
                int kp = kt * 32 + ((lane2 >> 4) << 3) + e;
                float val = 0.f;
                if (sl < cntg(g)) {
                    int u = unitOf(off1(g) + sl);
                    if (kp == 0) val = b0[u];
                    else if (kp - 1 <= g) val = W0[u * 64 + kp - 1];
                }
                W0f[idx] = f2bf(val);
            }
        }
    } else {
        for (int p = t; p < 1024; p += 512) b1p[p] = b1[unitOf(p)];
    }
}

// ---------------- made8: one window/step, spill-free (no dynamic reg indexing) ----------------
// Ownership: wave w finalizes h2[g] for g in [8w-1, 8w+6]  ==> owns tiles:
//   w=0: 0..7 (8) | w=1: 7..15 (9) | w=2: 15..23 (9) | w>=3: 8w..8w+7 (8)
// (straddle tiles 7/15 duplicated; each owner keeps a full independent accumulator)
// Publisher of step i = wave i>>3 = finalizer of h2[i-1]; chain h2->z->x->h1 same-wave.
// Non-publishers update z columns with LAG-1 from the parity buffer.
__global__ __launch_bounds__(NTHR) void made8(
    const float* __restrict__ uin, const float* __restrict__ b2,
    const short* __restrict__ W1f, const short* __restrict__ W2f,
    const short* __restrict__ W0f, const float* __restrict__ b1p,
    float* __restrict__ out) {

    __shared__ __align__(16) short h1b[2][16][40];   // parity buffers, [m][j], K-pad zeroed
    __shared__ __align__(16) short h2b[2][16][40];
    __shared__ __align__(16) short xhist[16][80];    // [m][k']: k'=0 -> 1.0, k'=i+1 -> x_i
    __shared__ __align__(16) float uT[64][16];
    __shared__ __align__(16) float xLs[16][68];
    __shared__ float ldjpart[8][16];

    const int t = threadIdx.x, lane = t & 63, wv = t >> 6;
    const int n = lane & 15, aq = lane >> 4;
    const int rowbase = blockIdx.x * 16;

    {   // zero all parity buffers + xhist (K pads must stay 0)
        int* z1 = (int*)&h1b[0][0][0];
        for (int idx = t; idx < 2 * 16 * 40 / 2; idx += NTHR) z1[idx] = 0;
        int* z2 = (int*)&h2b[0][0][0];
        for (int idx = t; idx < 2 * 16 * 40 / 2; idx += NTHR) z2[idx] = 0;
        int* z3 = (int*)&xhist[0][0];
        for (int idx = t; idx < 16 * 80 / 2; idx += NTHR) z3[idx] = 0;
    }
    if (t < 256) {
        int r = t >> 4, c0 = (t & 15) * 4;
        float4 v = *(const float4*)&uin[(long)(rowbase + r) * 64 + c0];
        uT[c0 + 0][r] = v.x; uT[c0 + 1][r] = v.y; uT[c0 + 2][r] = v.z; uT[c0 + 3][r] = v.w;
    }

    const int B = (wv == 0) ? 0 : (wv == 1) ? 7 : (wv == 2) ? 15 : 8 * wv;
    const int C = (wv == 1 || wv == 2) ? 9 : 8;

    f32x4 acc2[9];
#pragma unroll
    for (int s = 0; s < 9; ++s) {
        float bb = (s < C) ? b1p[(B + s) * 16 + n] : 0.f;
        acc2[s] = (f32x4){bb, bb, bb, bb};
    }
    f32x4 zacc;
    {
        int pc = wv * 16 + n;
        float bz = b2[(pc >> 1) + 64 * (pc & 1)];
        zacc = (f32x4){bz, bz, bz, bz};
    }

    bf16x8 w1f[9], w2g, w2gm1, w0f0, w0f1, w0f2;
#pragma unroll
    for (int s = 0; s < 9; ++s)
        if (s < C)
            w1f[s] = *(const bf16x8*)&W1f[(((long)0 * 64 + (B + s)) * 64 + lane) * 8]; // g=0
    w2g = *(const bf16x8*)&W2f[(((long)0 * 8 + wv) * 64 + lane) * 8];                  // g=0
    w2gm1 = w2g;
    {
        const long gb = 8 * wv;   // first group this wave computes h1 for
        w0f0 = *(const bf16x8*)&W0f[((gb * 4 + 0) * 64 + lane) * 8];
        w0f1 = *(const bf16x8*)&W0f[((gb * 4 + 1) * 64 + lane) * 8];
        w0f2 = *(const bf16x8*)&W0f[((gb * 4 + 2) * 64 + lane) * 8];
    }

    f32x4 ldjacc = {0.f, 0.f, 0.f, 0.f};
    BAR();
    if (t < 16) xhist[t][0] = (short)0x3F80;   // bias column = 1.0 (wave 0)
    float ureg[4];
#pragma unroll
    for (int r = 0; r < 4; ++r) ureg[r] = uT[8 * wv + (n >> 1)][aq * 4 + r];

#pragma unroll 1
    for (int i = 0; i < 64; ++i) {
        const int g = i - 1;
        const bool isPub = (wv == (i >> 3));

        if (g >= 0) {
            const int og = off1(g);
            const int tf0 = og >> 4;
            // bulk: acc2 += h1[g] * W1 on owned, still-live tiles
            const bf16x8 af1 = *(const bf16x8*)&h1b[(i + 1) & 1][n][aq * 8];
            const int s0 = tf0 - B;
#pragma unroll
            for (int s = 0; s < 9; ++s)
                if (s < C && s >= s0)
                    acc2[s] = __builtin_amdgcn_mfma_f32_16x16x32_bf16(af1, w1f[s], acc2[s], 0, 0, 0);
            {   // prefetch W1f group i (consumed next window)
                const int gp = (i < 63) ? i : 62;
                const int s0p = (off1(gp) >> 4) - B;
#pragma unroll
                for (int s = 0; s < 9; ++s)
                    if (s < C && s >= s0p)
                        w1f[s] = *(const bf16x8*)&W1f[(((long)gp * 64 + (B + s)) * 64 + lane) * 8];
            }
            // z lag-1 update for non-publishers
            const bool freshedPrev = (wv == ((i - 1) >> 3));
            if (!isPub && !freshedPrev && g >= 1) {
                const bf16x8 af2p = *(const bf16x8*)&h2b[(i - 1) & 1][n][aq * 8];
                zacc = __builtin_amdgcn_mfma_f32_16x16x32_bf16(af2p, w2gm1, zacc, 0, 0, 0);
            }
        }

        if (isPub) {
            if (g >= 0) {
                const int og = off1(g), cg = cntg(g);
                const int tf0 = og >> 4, tfl = (og + cg - 1) >> 4;
                if ((i & 7) == 0 && g >= 1) {   // run-start: catch up group g-1 (lag)
                    const bf16x8 af2p = *(const bf16x8*)&h2b[(i - 1) & 1][n][aq * 8];
                    zacc = __builtin_amdgcn_mfma_f32_16x16x32_bf16(af2p, w2gm1, zacc, 0, 0, 0);
                }
                // finalize h2[g]: SELECT-based extraction (no dynamic reg indexing)
                {
                    const int sT0 = tf0 - B;
                    f32x4 aT = acc2[0];
#pragma unroll
                    for (int s = 1; s < 9; ++s) aT = (s == sT0) ? acc2[s] : aT;
                    const int j = tf0 * 16 + n - og;
                    if (j >= 0 && j < cg) {
#pragma unroll
                        for (int r = 0; r < 4; ++r) {
                            float v = aT[r];
                            h2b[i & 1][aq * 4 + r][j] = f2bf(v > 0.f ? v : 0.f);
                        }
                    }
                }
                if (tfl != tf0) {
                    const int sT1 = tfl - B;
                    f32x4 aT = acc2[0];
#pragma unroll
                    for (int s = 1; s < 9; ++s) aT = (s == sT1) ? acc2[s] : aT;
                    const int j = tfl * 16 + n - og;
                    if (j < cg) {
#pragma unroll
                        for (int r = 0; r < 4; ++r) {
                            float v = aT[r];
                            h2b[i & 1][aq * 4 + r][j] = f2bf(v > 0.f ? v : 0.f);
                        }
                    }
                }
                if ((g == 16 || g == 17) && n == 0) {   // first 16-wide write per parity
#pragma unroll
                    for (int r = 0; r < 4; ++r) h2b[i & 1][aq * 4 + r][16] = 0;
                }
                // fresh z update with h2[g] (same-wave LDS round trip)
                const bf16x8 af2 = *(const bf16x8*)&h2b[i & 1][n][aq * 8];
                zacc = __builtin_amdgcn_mfma_f32_16x16x32_bf16(af2, w2g, zacc, 0, 0, 0);
            }
            // publish x_i: packed cols pc=2i (mu), 2i+1 (sigma) live in this wave
            {
                const int n0 = 2 * (i & 7);
                f32x4 sgv;
#pragma unroll
                for (int r = 0; r < 4; ++r) sgv[r] = __shfl_xor(zacc[r], 1);
                if (n == n0) {
#pragma unroll
                    for (int r = 0; r < 4; ++r) {
                        const float sg = sgv[r], mu = zacc[r];
                        const float x = ureg[r] * __expf(sg) + mu;
                        ldjacc[r] += sg;
                        const int m = aq * 4 + r;
                        xLs[m][i] = x;
                        if (i < 63) xhist[m][i + 1] = f2bf(x);
                    }
                }
            }
            if (i < 63) {   // h1[group i] (same-wave xhist round trip)
                const bf16x8 ax0 = *(const bf16x8*)&xhist[n][aq * 8];
                f32x4 d0 = {0.f, 0.f, 0.f, 0.f};
                d0 = __builtin_amdgcn_mfma_f32_16x16x32_bf16(ax0, w0f0, d0, 0, 0, 0);
                if (i >= 31) {
                    const bf16x8 ax1 = *(const bf16x8*)&xhist[n][32 + aq * 8];
                    d0 = __builtin_amdgcn_mfma_f32_16x16x32_bf16(ax1, w0f1, d0, 0, 0, 0);
                }
                f32x4 d1 = {0.f, 0.f, 0.f, 0.f};
                if (i < 16)
                    d1 = __builtin_amdgcn_mfma_f32_16x16x32_bf16(ax0, w0f2, d1, 0, 0, 0);
#pragma unroll
                for (int r = 0; r < 4; ++r) {
                    float v = d0[r];
                    h1b[i & 1][aq * 4 + r][n] = f2bf(v > 0.f ? v : 0.f);
                }
                if (n == 0) {
#pragma unroll
                    for (int r = 0; r < 4; ++r) {
                        float v = (i < 16) ? (d1[r] > 0.f ? d1[r] : 0.f) : 0.f;
                        h1b[i & 1][aq * 4 + r][16] = f2bf(v);
                    }
                }
                if (i + 1 < 63 && ((i + 1) >> 3) == wv) {   // next group still ours
                    const long gb = i + 1;
                    w0f0 = *(const bf16x8*)&W0f[((gb * 4 + 0) * 64 + lane) * 8];
                    w0f1 = *(const bf16x8*)&W0f[((gb * 4 + 1) * 64 + lane) * 8];
                    w0f2 = *(const bf16x8*)&W0f[((gb * 4 + 2) * 64 + lane) * 8];
                }
            }
        }

        // rotate W2 fragments: next window's fresh = group i, lag = group i-1
        w2gm1 = w2g;
        {
            const int gz = (i < 63) ? i : 62;
            w2g = *(const bf16x8*)&W2f[(((long)gz * 8 + wv) * 64 + lane) * 8];
        }
        BAR();
    }

    // ldj: publisher lanes are even n; reduce within wave then across waves
#pragma unroll
    for (int r = 0; r < 4; ++r) {
        float v = ldjacc[r];
        v += __shfl_xor(v, 2);
        v += __shfl_xor(v, 4);
        v += __shfl_xor(v, 8);
        if (n == 0) ldjpart[wv][aq * 4 + r] = v;
    }
    BAR();

    if (t < 256) {
        int r = t >> 4, c = (t & 15) * 4;
        float4 v;
        v.x = xLs[r][c]; v.y = xLs[r][c + 1]; v.z = xLs[r][c + 2]; v.w = xLs[r][c + 3];
        *(float4*)&out[(long)(rowbase + r) * 64 + c] = v;
    }
    if (t < 16) {
        float s = 0.f;
#pragma unroll
        for (int w = 0; w < 8; ++w) s += ldjpart[w][t];
        out[(long)BATCH * 64 + rowbase + t] = s;
    }
}

extern "C" void kernel_launch(void* const* d_in, const int* in_sizes, int n_in,
                              void* d_out, int out_size, void* d_ws, size_t ws_size,
                              hipStream_t stream) {
    (void)in_sizes; (void)n_in; (void)out_size; (void)ws_size;
    const float* u  = (const float*)d_in[0];
    const float* W0 = (const float*)d_in[1];
    const float* b0 = (const float*)d_in[2];
    const float* W1 = (const float*)d_in[3];
    const float* b1 = (const float*)d_in[4];
    const float* W2 = (const float*)d_in[5];
    const float* b2 = (const float*)d_in[6];
    float* out = (float*)d_out;

    // d_ws layout (bytes): W1f 4,128,768 | W2f 516,096 | W0f 258,048 | b1p 4,096
    short* W1f = (short*)d_ws;
    short* W2f = (short*)((char*)d_ws + 4128768);
    short* W0f = (short*)((char*)d_ws + 4128768 + 516096);
    float* b1p = (float*)((char*)d_ws + 4128768 + 516096 + 258048);

    prep8<<<dim3(89), dim3(512), 0, stream>>>(W0, b0, W1, b1, W2, W1f, W2f, W0f, b1p);
    made8<<<dim3(BATCH / 16), dim3(NTHR), 0, stream>>>(u, b2, W1f, W2f, W0f, b1p, out);
}